// Round 1
// baseline (258.550 us; speedup 1.0000x reference)
//
#include <hip/hip_runtime.h>

// RBDispatcher R3: section-split double-gather + concat (pure data movement).
//   out[0 .. n_s2)         = x[ idx_s1[ idx_s2[r] ] / top_k ]   (random gather)
//   out[n_s2 .. n_s2+n_s1) = x[ idx_s1[r - n_s2] / top_k ]      (monotone copy)
//
// R3 changes vs R2 (fused wave-per-row, ~115us kernel, dur 254.8):
//  - TWO sequential kernels instead of one fused kernel:
//      S1 first: sorted idx_s1 => src monotone => a streaming expansion copy
//        (sequential reads AND writes; also warms the 256MiB LLC with all of x).
//      S2 second: random row gather now hits LLC-resident x; HBM sees ~writes only.
//  - Full-row register batching: 8x dwordx4 loads -> 8x nontemporal stores
//    (read-burst / write-burst instead of load/store ping-pong at 1KiB grain).
//  - Multi-row waves (4 rows/wave S1, 2 rows/wave S2) with int4/int2 index
//    loads to amortize the dependent index-chain latency.

typedef float v4f __attribute__((ext_vector_type(4)));

// Full-row copy for d==2048: 8x16B/lane loads into regs, then 8 streaming stores.
__device__ __forceinline__ void copy_row_2048(const float* __restrict__ src,
                                              float* __restrict__ dst,
                                              int lane) {
  const v4f* __restrict__ sp = (const v4f*)src;
  v4f* __restrict__ dp = (v4f*)dst;
  v4f t[8];
#pragma unroll
  for (int i = 0; i < 8; ++i) t[i] = sp[lane + 64 * i];      // cached reads (x -> LLC)
#pragma unroll
  for (int i = 0; i < 8; ++i)
    __builtin_nontemporal_store(t[i], dp + lane + 64 * i);   // streaming writes
}

// S1 section: out_s1[r] = x[idx_s1[r]/top_k]. idx_s1 sorted => monotone copy.
// 4 waves/block, 4 consecutive rows per wave (block covers 16 rows).
__global__ __launch_bounds__(256) void rb_s1_kernel(
    const float* __restrict__ x, const int* __restrict__ idx_s1,
    const int* __restrict__ top_k_ptr, float* __restrict__ out_s1,
    int n_s1) {
  const int wave = threadIdx.x >> 6;
  const int lane = threadIdx.x & 63;
  const int r0 = (blockIdx.x * 4 + wave) * 4;
  if (r0 >= n_s1) return;
  const int tk = *top_k_ptr;

  if (r0 + 3 < n_s1) {
    const int4 iv = *(const int4*)(idx_s1 + r0);  // one 16B index load / 4 rows
    int s[4] = {iv.x / tk, iv.y / tk, iv.z / tk, iv.w / tk};
#pragma unroll
    for (int k = 0; k < 4; ++k)
      copy_row_2048(x + (size_t)s[k] * 2048,
                    out_s1 + (size_t)(r0 + k) * 2048, lane);
  } else {
    for (int k = 0; k < 4 && r0 + k < n_s1; ++k) {
      const int sv = idx_s1[r0 + k] / tk;
      copy_row_2048(x + (size_t)sv * 2048,
                    out_s1 + (size_t)(r0 + k) * 2048, lane);
    }
  }
}

// S2 section: out[r] = x[idx_s1[idx_s2[r]]/top_k]. Random gather; runs after S1
// so x is LLC-resident. 2 rows per wave (more blocks => latency hiding for the
// two-deep dependent index chain).
__global__ __launch_bounds__(256) void rb_s2_kernel(
    const float* __restrict__ x, const int* __restrict__ idx_s1,
    const int* __restrict__ idx_s2, const int* __restrict__ top_k_ptr,
    float* __restrict__ out, int n_s2) {
  const int wave = threadIdx.x >> 6;
  const int lane = threadIdx.x & 63;
  const int r0 = (blockIdx.x * 4 + wave) * 2;
  if (r0 >= n_s2) return;
  const int tk = *top_k_ptr;

  if (r0 + 1 < n_s2) {
    const int2 jv = *(const int2*)(idx_s2 + r0);
    const int s0 = idx_s1[jv.x] / tk;
    const int s1 = idx_s1[jv.y] / tk;
    copy_row_2048(x + (size_t)s0 * 2048, out + (size_t)r0 * 2048, lane);
    copy_row_2048(x + (size_t)s1 * 2048, out + (size_t)(r0 + 1) * 2048, lane);
  } else {
    const int s0 = idx_s1[idx_s2[r0]] / tk;
    copy_row_2048(x + (size_t)s0 * 2048, out + (size_t)r0 * 2048, lane);
  }
}

// Generic fallback (any d): the R2 fused wave-per-row kernel.
__global__ __launch_bounds__(256) void rb_dispatch_generic(
    const float* __restrict__ x,
    const int* __restrict__ idx_s1,
    const int* __restrict__ idx_s2,
    const int* __restrict__ top_k_ptr,
    float* __restrict__ out,
    int n_s2, int n_rows, int nvec) {
  const int wave = threadIdx.x >> 6;
  const int lane = threadIdx.x & 63;
  const int row = blockIdx.x * 4 + wave;
  if (row >= n_rows) return;
  const int top_k = *top_k_ptr;
  int src;
  if (row < n_s2) src = idx_s1[idx_s2[row]] / top_k;
  else            src = idx_s1[row - n_s2] / top_k;
  const int d = nvec * 4;
  const v4f* __restrict__ sp = (const v4f*)(x + (size_t)src * (size_t)d);
  v4f* __restrict__ dp = (v4f*)(out + (size_t)row * (size_t)d);
#pragma unroll 4
  for (int i = lane; i < nvec; i += 64) {
    v4f v = sp[i];
    __builtin_nontemporal_store(v, dp + i);
  }
}

extern "C" void kernel_launch(void* const* d_in, const int* in_sizes, int n_in,
                              void* d_out, int out_size, void* d_ws, size_t ws_size,
                              hipStream_t stream) {
  const float* x      = (const float*)d_in[0];
  const int*   idx_s1 = (const int*)d_in[1];
  const int*   idx_s2 = (const int*)d_in[2];
  // d_in[3] = n_tokens (unused), d_in[4] = top_k (device scalar)
  const int*   top_k  = (const int*)d_in[4];
  float*       out    = (float*)d_out;

  const int n_s1   = in_sizes[1];       // 16384
  const int n_s2   = in_sizes[2];       // 8192
  const int n_rows = n_s1 + n_s2;       // 24576
  const int d      = out_size / n_rows; // 2048 (out_size in elements)

  if (d == 2048) {
    // S1 first: streaming expansion copy, warms LLC with all of x.
    const int grid1 = (n_s1 + 15) / 16;   // 16 rows/block
    rb_s1_kernel<<<grid1, 256, 0, stream>>>(
        x, idx_s1, top_k, out + (size_t)n_s2 * 2048, n_s1);
    // S2 second: random gather against LLC-resident x.
    const int grid2 = (n_s2 + 7) / 8;     // 8 rows/block
    rb_s2_kernel<<<grid2, 256, 0, stream>>>(
        x, idx_s1, idx_s2, top_k, out, n_s2);
  } else {
    const int nvec = d / 4;
    const int grid = (n_rows + 3) / 4;
    rb_dispatch_generic<<<grid, 256, 0, stream>>>(
        x, idx_s1, idx_s2, top_k, out, n_s2, n_rows, nvec);
  }
}

// Round 2
// 255.224 us; speedup vs baseline: 1.0130x; 1.0130x over previous
//
#include <hip/hip_runtime.h>

// RBDispatcher R4: fused double-gather + concat, software-pipelined rows.
//   out[0 .. n_s2)         = x[ idx_s1[ idx_s2[r] ] / top_k ]   (random gather)
//   out[n_s2 .. n_s2+n_s1) = x[ idx_s1[r - n_s2] / top_k ]      (monotone copy)
//
// R4 changes vs R3 (split kernels, read-burst/write-burst per row, 258.6us):
//  - Back to ONE dispatch (R3's second launch bought nothing, cost ~4us gap).
//    s2 rows map to the lowest block ids so the 2-deep index chains start first.
//  - 2-row register double buffer per wave: issue row k+1's 8 loads BEFORE
//    row k's stores. Every prior version drained vmcnt(0) before storing, so
//    each wave's read pipe went empty once per row; now >=16KB of reads stay
//    in flight across the store bursts (compiler can stage vmcnt(8)).
//  - __launch_bounds__(256,4): cap 128 VGPR so 16 waves/CU remain resident.

typedef float v4f __attribute__((ext_vector_type(4)));

__device__ __forceinline__ void load_row(const float* __restrict__ src,
                                         int lane, v4f t[8]) {
  const v4f* __restrict__ sp = (const v4f*)src;
#pragma unroll
  for (int i = 0; i < 8; ++i) t[i] = sp[lane + 64 * i];   // cached: keep x in L2/LLC
}

__device__ __forceinline__ void store_row_nt(float* __restrict__ dst,
                                             int lane, const v4f t[8]) {
  v4f* __restrict__ dp = (v4f*)dst;
#pragma unroll
  for (int i = 0; i < 8; ++i)
    __builtin_nontemporal_store(t[i], dp + lane + 64 * i); // streaming: don't churn LLC
}

// Fast path, d==2048, n_rows % 4 == 0.
// wave g handles rows [4g, 4g+4): s2 section first (blocks 0..n_s2/16).
__global__ __launch_bounds__(256, 4) void rb_dispatch_r4(
    const float* __restrict__ x,
    const int* __restrict__ idx_s1,
    const int* __restrict__ idx_s2,
    const int* __restrict__ top_k_ptr,
    float* __restrict__ out,
    int n_s2, int n_rows) {
  const int wave = threadIdx.x >> 6;
  const int lane = threadIdx.x & 63;
  const int r0 = (blockIdx.x * 4 + wave) * 4;
  if (r0 >= n_rows) return;
  const int tk = *top_k_ptr;

  int s[4];
#pragma unroll
  for (int k = 0; k < 4; ++k) {
    const int r = r0 + k;                       // wave-uniform -> scalarized
    s[k] = (r < n_s2) ? (idx_s1[idx_s2[r]] / tk)
                      : (idx_s1[r - n_s2] / tk);
  }

  const float* __restrict__ src0 = x + (size_t)s[0] * 2048;
  const float* __restrict__ src1 = x + (size_t)s[1] * 2048;
  const float* __restrict__ src2 = x + (size_t)s[2] * 2048;
  const float* __restrict__ src3 = x + (size_t)s[3] * 2048;
  float* __restrict__ dst = out + (size_t)r0 * 2048;

  v4f A[8], B[8];
  // 2-deep pipeline: next row's loads are issued before this row's stores,
  // so the read pipe never drains to vmcnt(0) mid-wave.
  load_row(src0, lane, A);
  load_row(src1, lane, B);
  store_row_nt(dst + 0 * 2048, lane, A);   // waits vmcnt(8): B still in flight
  load_row(src2, lane, A);
  store_row_nt(dst + 1 * 2048, lane, B);
  load_row(src3, lane, B);
  store_row_nt(dst + 2 * 2048, lane, A);
  store_row_nt(dst + 3 * 2048, lane, B);
}

// Generic fallback (any d / row count): R2 fused wave-per-row kernel.
__global__ __launch_bounds__(256) void rb_dispatch_generic(
    const float* __restrict__ x,
    const int* __restrict__ idx_s1,
    const int* __restrict__ idx_s2,
    const int* __restrict__ top_k_ptr,
    float* __restrict__ out,
    int n_s2, int n_rows, int nvec) {
  const int wave = threadIdx.x >> 6;
  const int lane = threadIdx.x & 63;
  const int row = blockIdx.x * 4 + wave;
  if (row >= n_rows) return;
  const int top_k = *top_k_ptr;
  int src;
  if (row < n_s2) src = idx_s1[idx_s2[row]] / top_k;
  else            src = idx_s1[row - n_s2] / top_k;
  const int d = nvec * 4;
  const v4f* __restrict__ sp = (const v4f*)(x + (size_t)src * (size_t)d);
  v4f* __restrict__ dp = (v4f*)(out + (size_t)row * (size_t)d);
#pragma unroll 4
  for (int i = lane; i < nvec; i += 64) {
    v4f v = sp[i];
    __builtin_nontemporal_store(v, dp + i);
  }
}

extern "C" void kernel_launch(void* const* d_in, const int* in_sizes, int n_in,
                              void* d_out, int out_size, void* d_ws, size_t ws_size,
                              hipStream_t stream) {
  const float* x      = (const float*)d_in[0];
  const int*   idx_s1 = (const int*)d_in[1];
  const int*   idx_s2 = (const int*)d_in[2];
  // d_in[3] = n_tokens (unused), d_in[4] = top_k (device scalar)
  const int*   top_k  = (const int*)d_in[4];
  float*       out    = (float*)d_out;

  const int n_s1   = in_sizes[1];       // 16384
  const int n_s2   = in_sizes[2];       // 8192
  const int n_rows = n_s1 + n_s2;       // 24576
  const int d      = out_size / n_rows; // 2048

  if (d == 2048 && (n_rows & 3) == 0 && (n_s2 & 3) == 0) {
    // 16 rows per block; 24576/16 = 1536 blocks, no tail.
    const int grid = n_rows / 16;
    rb_dispatch_r4<<<grid, 256, 0, stream>>>(
        x, idx_s1, idx_s2, top_k, out, n_s2, n_rows);
  } else {
    const int nvec = d / 4;
    const int grid = (n_rows + 3) / 4;
    rb_dispatch_generic<<<grid, 256, 0, stream>>>(
        x, idx_s1, idx_s2, top_k, out, n_s2, n_rows, nvec);
  }
}